// Round 16
// baseline (138.525 us; speedup 1.0000x reference)
//
#include <hip/hip_runtime.h>
#include <cmath>

typedef short bf16x8 __attribute__((ext_vector_type(8)));
typedef float f32x2 __attribute__((ext_vector_type(2)));
typedef float f32x4 __attribute__((ext_vector_type(4)));
typedef float f32x16 __attribute__((ext_vector_type(16)));

#define NSEQ 4096
#define BATCH 2
#define DIM 512
#define HEADS 8
#define NROWS (BATCH * NSEQ)   // 8192
#define QKVN (3 * DIM)         // 1536

__device__ __forceinline__ unsigned short f2bf(float f) {
  unsigned int u = __float_as_uint(f);
  u += 0x7fffu + ((u >> 16) & 1u);
  return (unsigned short)(u >> 16);
}
__device__ __forceinline__ float bf2f(unsigned short h) {
  return __uint_as_float(((unsigned int)h) << 16);
}
__device__ __forceinline__ void gload16(const unsigned short* g, unsigned short* l) {
  __builtin_amdgcn_global_load_lds((const __attribute__((address_space(1))) unsigned int*)g,
                                   (__attribute__((address_space(3))) unsigned int*)l, 16, 0, 0);
}

// ---------------- fused prep: trig tables (HW sin/cos) + weight cvts + LayerNorm ----------------
// blocks [0,2048): tables; [2048,5120): wqkv cvt; [5120,6144): wout cvt; [6144,8192): LN
__global__ __launch_bounds__(256) void k_prep(const float* __restrict__ rot,
                                              float* __restrict__ cosT,
                                              float* __restrict__ sinT,
                                              const float* __restrict__ wqkv,
                                              unsigned short* __restrict__ wqkb,
                                              const float* __restrict__ wout,
                                              unsigned short* __restrict__ wob,
                                              const float* __restrict__ x,
                                              const float* __restrict__ lnw,
                                              const float* __restrict__ lnb,
                                              unsigned short* __restrict__ xn) {
  const float INV2PI = 0.15915494309f;
  int bid = blockIdx.x;
  int t = threadIdx.x;
  if (bid < 2048) {
    int i = bid * 256 + t;
    float rv = rot[i] * INV2PI;           // v_sin/v_cos take revolutions
    cosT[i] = __builtin_amdgcn_cosf(rv);
    sinT[i] = __builtin_amdgcn_sinf(rv);
  } else if (bid < 5120) {
    int i = (bid - 2048) * 256 + t;
    wqkb[i] = f2bf(wqkv[i]);
  } else if (bid < 6144) {
    int i = (bid - 5120) * 256 + t;
    wob[i] = f2bf(wout[i]);
  } else {
    int row = (bid - 6144) * 4 + (t >> 6);
    int lane = t & 63;
    const float* xr = x + (size_t)row * DIM;
    float v[8];
    float s = 0.f;
#pragma unroll
    for (int j = 0; j < 8; ++j) { v[j] = xr[lane + j * 64]; s += v[j]; }
#pragma unroll
    for (int m = 1; m < 64; m <<= 1) s += __shfl_xor(s, m);
    float mu = s * (1.0f / DIM);
    float q = 0.f;
#pragma unroll
    for (int j = 0; j < 8; ++j) { float d = v[j] - mu; q += d * d; }
#pragma unroll
    for (int m = 1; m < 64; m <<= 1) q += __shfl_xor(q, m);
    float rs = rsqrtf(q * (1.0f / DIM) + 1e-5f);
#pragma unroll
    for (int j = 0; j < 8; ++j) {
      int col = lane + j * 64;
      xn[(size_t)row * DIM + col] = f2bf((v[j] - mu) * rs * lnw[col] + lnb[col]);
    }
  }
}

// ---------------- GEMM (qkv): C = A[M][K] * B[N][K]^T — 3-buffer ring, counted vmcnt ----
// 128x128 tile, 4 waves. Per step: stage(t+1); s_waitcnt vmcnt(4); s_barrier; compute.
__global__ __launch_bounds__(256) void k_gemm(const unsigned short* __restrict__ A,
                                              const unsigned short* __restrict__ B,
                                              unsigned short* __restrict__ C,
                                              int M, int N, int K) {
  __shared__ __align__(16) unsigned short As[3][128 * 32];
  __shared__ __align__(16) unsigned short Bs[3][128 * 32];
  int bm = blockIdx.x, bn = blockIdx.y;
  int tid = threadIdx.x;
  int lane = tid & 63, w = tid >> 6;
  int wm = (w >> 1) << 6, wn = (w & 1) << 6;
  f32x4 acc[4][4] = {};

#define GSTAGE(KT, BUF) do { \
  _Pragma("unroll") \
  for (int i = 0; i < 2; ++i) { \
    int c = tid + (i << 8); \
    int row = c >> 2, kc = (c & 3) << 3; \
    gload16(A + (size_t)(bm * 128 + row) * K + (KT) + kc, &As[BUF][(w * 64 + i * 256) * 8]); \
    gload16(B + (size_t)(bn * 128 + row) * K + (KT) + kc, &Bs[BUF][(w * 64 + i * 256) * 8]); \
  } } while (0)

  GSTAGE(0, 0);
  int nk = K >> 5;
  int rbuf = 0, wbuf = 1;
  for (int t = 0; t < nk; ++t) {
    if (t + 1 < nk) {
      GSTAGE((t + 1) << 5, wbuf);
      asm volatile("s_waitcnt vmcnt(4)" ::: "memory");
    } else {
      asm volatile("s_waitcnt vmcnt(0)" ::: "memory");
    }
    __builtin_amdgcn_s_barrier();
    asm volatile("" ::: "memory");
    bf16x8 af[4], bfr[4];
#pragma unroll
    for (int mi = 0; mi < 4; ++mi)
      af[mi] = *(const bf16x8*)&As[rbuf][(wm + mi * 16 + (lane & 15)) * 32 + ((lane >> 4) << 3)];
#pragma unroll
    for (int ni = 0; ni < 4; ++ni)
      bfr[ni] = *(const bf16x8*)&Bs[rbuf][(wn + ni * 16 + (lane & 15)) * 32 + ((lane >> 4) << 3)];
#pragma unroll
    for (int mi = 0; mi < 4; ++mi)
#pragma unroll
      for (int ni = 0; ni < 4; ++ni)
        acc[mi][ni] = __builtin_amdgcn_mfma_f32_16x16x32_bf16(af[mi], bfr[ni], acc[mi][ni], 0, 0, 0);
    rbuf = (rbuf == 2) ? 0 : rbuf + 1;
    wbuf = (wbuf == 2) ? 0 : wbuf + 1;
  }
#undef GSTAGE
#pragma unroll
  for (int mi = 0; mi < 4; ++mi) {
#pragma unroll
    for (int ni = 0; ni < 4; ++ni) {
#pragma unroll
      for (int r = 0; r < 4; ++r) {
        int gm = bm * 128 + wm + mi * 16 + ((lane >> 4) << 2) + r;
        int gn = bn * 128 + wn + ni * 16 + (lane & 15);
        C[(size_t)gm * N + gn] = f2bf(acc[mi][ni][r]);
      }
    }
  }
}

// ---------------- output GEMM with fused combine: out = combine(opart,lpart)*wob^T + bias ----
// 64x128 tile, 4 waves (wave tile 32x64). A-tile (64 rows x 32 cols) reg-staged: each
// thread computes 8 bf16 of the combined+inverse-RoPE'd attention output and ds_writes.
// Steady-state wait: vmcnt(2) (B(t+1) in flight; A-loads already consumed) + lgkmcnt(0).
__global__ __launch_bounds__(256) void k_gemm_out(const unsigned short* __restrict__ opart,
                                                  const float* __restrict__ lpart,
                                                  const float* __restrict__ cosT,
                                                  const float* __restrict__ sinT,
                                                  const unsigned short* __restrict__ B,
                                                  float* __restrict__ C,
                                                  const float* __restrict__ bias) {
  const int K = DIM, N = DIM;
  const size_t HOFF = (size_t)16 * NSEQ;
  __shared__ __align__(16) unsigned short As[3][64 * 32];
  __shared__ __align__(16) unsigned short Bs[3][128 * 32];
  int bm = blockIdx.x, bn = blockIdx.y;
  int tid = threadIdx.x;
  int lane = tid & 63, w = tid >> 6;
  int wm = (w >> 1) << 5, wn = (w & 1) << 6;
  f32x4 acc[2][4] = {};

  // A-stage geometry (fixed per thread): row = tid>>2 (0..63), kc = (tid&3)*8
  int arow = tid >> 2, akc = (tid & 3) << 3;
  int grow = bm * 64 + arow;
  int b = grow >> 12, q = grow & (NSEQ - 1);
  const float* cbase = cosT + ((size_t)b * NSEQ + q) * 64;
  const float* sbase = sinT + ((size_t)b * NSEQ + q) * 64;

#define ASTAGE(KT, BUF) do { \
  int gc = (KT) + akc; \
  int h = gc >> 6, d0 = gc & 63; \
  size_t i0 = (size_t)(b * 8 + h) * NSEQ + q; \
  float l = lpart[i0] + lpart[i0 + HOFF]; \
  float inv = 1.0f / l; \
  uint4 u0 = *(const uint4*)(opart + i0 * 64 + d0); \
  uint4 u1 = *(const uint4*)(opart + (i0 + HOFF) * 64 + d0); \
  float4 cA = *(const float4*)(cbase + d0); \
  float4 cB = *(const float4*)(cbase + d0 + 4); \
  float4 sA = *(const float4*)(sbase + d0); \
  float4 sB = *(const float4*)(sbase + d0 + 4); \
  float o0 = (bf2f((unsigned short)(u0.x & 0xffff)) + bf2f((unsigned short)(u1.x & 0xffff))) * inv; \
  float o1 = (bf2f((unsigned short)(u0.x >> 16))    + bf2f((unsigned short)(u1.x >> 16)))    * inv; \
  float o2 = (bf2f((unsigned short)(u0.y & 0xffff)) + bf2f((unsigned short)(u1.y & 0xffff))) * inv; \
  float o3 = (bf2f((unsigned short)(u0.y >> 16))    + bf2f((unsigned short)(u1.y >> 16)))    * inv; \
  float o4 = (bf2f((unsigned short)(u0.z & 0xffff)) + bf2f((unsigned short)(u1.z & 0xffff))) * inv; \
  float o5 = (bf2f((unsigned short)(u0.z >> 16))    + bf2f((unsigned short)(u1.z >> 16)))    * inv; \
  float o6 = (bf2f((unsigned short)(u0.w & 0xffff)) + bf2f((unsigned short)(u1.w & 0xffff))) * inv; \
  float o7 = (bf2f((unsigned short)(u0.w >> 16))    + bf2f((unsigned short)(u1.w >> 16)))    * inv; \
  union { unsigned short u[8]; bf16x8 v; } y; \
  y.u[0] = f2bf(o0 * cA.x + o1 * sA.x); \
  y.u[1] = f2bf(o1 * cA.y - o0 * sA.y); \
  y.u[2] = f2bf(o2 * cA.z + o3 * sA.z); \
  y.u[3] = f2bf(o3 * cA.w - o2 * sA.w); \
  y.u[4] = f2bf(o4 * cB.x + o5 * sB.x); \
  y.u[5] = f2bf(o5 * cB.y - o4 * sB.y); \
  y.u[6] = f2bf(o6 * cB.z + o7 * sB.z); \
  y.u[7] = f2bf(o7 * cB.w - o6 * sB.w); \
  *(bf16x8*)&As[BUF][tid * 8] = y.v; \
} while (0)

#define BSTAGE(KT, BUF) do { \
  _Pragma("unroll") \
  for (int i = 0; i < 2; ++i) { \
    int c = tid + (i << 8); \
    int row = c >> 2, kc = (c & 3) << 3; \
    gload16(B + (size_t)(bn * 128 + row) * K + (KT) + kc, &Bs[BUF][(w * 64 + i * 256) * 8]); \
  } } while (0)

  BSTAGE(0, 0);
  ASTAGE(0, 0);
  const int nk = K >> 5;  // 16
  int rbuf = 0, wbuf = 1;
  for (int t = 0; t < nk; ++t) {
    if (t + 1 < nk) {
      BSTAGE((t + 1) << 5, wbuf);
      ASTAGE((t + 1) << 5, wbuf);
      asm volatile("s_waitcnt vmcnt(2) lgkmcnt(0)" ::: "memory");
    } else {
      asm volatile("s_waitcnt vmcnt(0) lgkmcnt(0)" ::: "memory");
    }
    __builtin_amdgcn_s_barrier();
    asm volatile("" ::: "memory");
    bf16x8 af[2], bfr[4];
#pragma unroll
    for (int mi = 0; mi < 2; ++mi)
      af[mi] = *(const bf16x8*)&As[rbuf][(wm + mi * 16 + (lane & 15)) * 32 + ((lane >> 4) << 3)];
#pragma unroll
    for (int ni = 0; ni < 4; ++ni)
      bfr[ni] = *(const bf16x8*)&Bs[rbuf][(wn + ni * 16 + (lane & 15)) * 32 + ((lane >> 4) << 3)];
#pragma unroll
    for (int mi = 0; mi < 2; ++mi)
#pragma unroll
      for (int ni = 0; ni < 4; ++ni)
        acc[mi][ni] = __builtin_amdgcn_mfma_f32_16x16x32_bf16(af[mi], bfr[ni], acc[mi][ni], 0, 0, 0);
    rbuf = (rbuf == 2) ? 0 : rbuf + 1;
    wbuf = (wbuf == 2) ? 0 : wbuf + 1;
  }
#undef ASTAGE
#undef BSTAGE
#pragma unroll
  for (int mi = 0; mi < 2; ++mi) {
#pragma unroll
    for (int ni = 0; ni < 4; ++ni) {
#pragma unroll
      for (int r = 0; r < 4; ++r) {
        int gm = bm * 64 + wm + mi * 16 + ((lane >> 4) << 2) + r;
        int gn = bn * 128 + wn + ni * 16 + (lane & 15);
        C[(size_t)gm * N + gn] = acc[mi][ni][r] + bias[gn];
      }
    }
  }
}

// ------ RoPE + head split (+ V transpose); Q pre-scaled by 0.125*log2(e) (exp2-domain) ------
__global__ __launch_bounds__(256) void k_rope_split(const unsigned short* __restrict__ qkv,
                                                    const float* __restrict__ cosT,
                                                    const float* __restrict__ sinT,
                                                    unsigned short* __restrict__ qh,
                                                    unsigned short* __restrict__ kh,
                                                    unsigned short* __restrict__ vt) {
  __shared__ unsigned short vs[128][65];
  const float QSC = 0.125f * 1.44269504f;
  int nt = blockIdx.x, bh = blockIdx.y;
  int b = bh >> 3, h = bh & 7;
  int n0 = nt * 128;
  int t = threadIdx.x;
  int sub = t >> 3, cc = t & 7;
#pragma unroll
  for (int rr = 0; rr < 4; ++rr) {
    int row = rr * 32 + sub;
    int n = n0 + row;
    size_t base = ((size_t)(b * NSEQ + n)) * QKVN + h * 64 + cc * 8;
    const float* cb = cosT + ((size_t)(b * NSEQ + n)) * 64 + cc * 8;
    const float* sb = sinT + ((size_t)(b * NSEQ + n)) * 64 + cc * 8;
    float c[8], sn[8];
#pragma unroll
    for (int j = 0; j < 8; ++j) { c[j] = cb[j]; sn[j] = sb[j]; }
    bf16x8 qv = *(const bf16x8*)(qkv + base);
    bf16x8 kv = *(const bf16x8*)(qkv + base + 512);
    bf16x8 vv = *(const bf16x8*)(qkv + base + 1024);
    union { bf16x8 v; unsigned short u[8]; } yq, yk;
#pragma unroll
    for (int j = 0; j < 8; j += 2) {
      {
        float e = bf2f((unsigned short)qv[j]), o = bf2f((unsigned short)qv[j + 1]);
        yq.u[j]     = f2bf((e * c[j] - o * sn[j]) * QSC);
        yq.u[j + 1] = f2bf((o * c[j + 1] + e * sn[j + 1]) * QSC);
      }
      {
        float e = bf2f((unsigned short)kv[j]), o = bf2f((unsigned short)kv[j + 1]);
        yk.u[j]     = f2bf(e * c[j] - o * sn[j]);
        yk.u[j + 1] = f2bf(o * c[j + 1] + e * sn[j + 1]);
      }
      {
        float e = bf2f((unsigned short)vv[j]), o = bf2f((unsigned short)vv[j + 1]);
        vs[row][cc * 8 + j]     = f2bf(e * c[j] - o * sn[j]);
        vs[row][cc * 8 + j + 1] = f2bf(o * c[j + 1] + e * sn[j + 1]);
      }
    }
    *(bf16x8*)(qh + ((size_t)bh * NSEQ + n) * 64 + cc * 8) = yq.v;
    *(bf16x8*)(kh + ((size_t)bh * NSEQ + n) * 64 + cc * 8) = yk.v;
  }
  __syncthreads();
  int d = t >> 2, c4 = t & 3;
#pragma unroll
  for (int g = 0; g < 4; ++g) {
    union { bf16x8 v; unsigned short u[8]; } tv;
#pragma unroll
    for (int j = 0; j < 8; ++j) tv.u[j] = vs[c4 * 32 + g * 8 + j][d];
    *(bf16x8*)(vt + ((size_t)bh * 64 + d) * NSEQ + n0 + c4 * 32 + g * 8) = tv.v;
  }
}

// ---------------- Flash attention (= round-15, unchanged): KV-split-2, 64q/wave ----
// 512 blocks x 4 waves; 4-buffer LDS ring, depth-2 prefetch, counted vmcnt(8) + raw
// s_barrier per tile (never drain in steady state). shfl_xor exchange (proven).
__global__ __launch_bounds__(256, 2) void k_attn(const unsigned short* __restrict__ Qh,
                                                 const unsigned short* __restrict__ Kh,
                                                 const unsigned short* __restrict__ VT,
                                                 unsigned short* __restrict__ opart,
                                                 float* __restrict__ lpart) {
  __shared__ __align__(16) unsigned short Ks[4][64 * 64];
  __shared__ __align__(16) unsigned short Vs[4][64 * 64];
  int bid = blockIdx.x;
  int bh   = (bid & 7) + 8 * ((bid >> 7) & 1);  // XCD-pinned: bh%8 == bid%8
  int qt   = (bid >> 3) & 15;
  int half = (bid >> 8) & 1;
  int tid = threadIdx.x;
  int w = tid >> 6, lane = tid & 63;
  int lq = lane & 31, hi = lane >> 5;
  int q0 = qt * 256 + w * 64;
  int kv0 = half * 2048;

  const unsigned short* Kbh = Kh + (size_t)bh * NSEQ * 64;
  const unsigned short* Vbh = VT + (size_t)bh * 64 * NSEQ;

  const unsigned short* QbA = Qh + ((size_t)bh * NSEQ + q0 + lq) * 64 + hi * 8;
  const unsigned short* QbB = QbA + 32 * 64;
  bf16x8 qfA[4], qfB[4];
#pragma unroll
  for (int j = 0; j < 4; ++j) {
    qfA[j] = *(const bf16x8*)(QbA + j * 16);
    qfB[j] = *(const bf16x8*)(QbB + j * 16);
  }

  // staging chunk geometry: chunk c -> row r=c>>3, source 16B slot (c&7)^(r&7)
  int c0 = w * 64 + lane;
  int r0 = c0 >> 3, sw0 = ((c0 & 7) ^ (r0 & 7)) << 3;
  int c1 = c0 + 256;
  int r1 = c1 >> 3, sw1 = ((c1 & 7) ^ (r1 & 7)) << 3;
  int ld0 = (w * 64) * 8, ld1 = (256 + w * 64) * 8;

  f32x16 accA0 = (f32x16)0.0f, accA1 = (f32x16)0.0f;
  f32x16 accB0 = (f32x16)0.0f, accB1 = (f32x16)0.0f;
  float lA = 0.f, lB = 0.f;
  int swz = (lq & 7) << 4;

#define STAGE(T, BUF) do { \
  int tg_ = kv0 + (T) * 64; \
  gload16(Kbh + ((size_t)tg_ + r0) * 64 + sw0, &Ks[BUF][ld0]); \
  gload16(Kbh + ((size_t)tg_ + r1) * 64 + sw1, &Ks[BUF][ld1]); \
  gload16(Vbh + (size_t)r0 * NSEQ + tg_ + sw0, &Vs[BUF][ld0]); \
  gload16(Vbh + (size_t)r1 * NSEQ + tg_ + sw1, &Vs[BUF][ld1]); \
} while (0)

  // prologue: prefetch tiles 0 and 1 (8 loads in flight)
  STAGE(0, 0);
  STAGE(1, 1);

  for (int t = 0; t < 32; ++t) {
    int rd = t & 3;
    if (t < 30) {
      STAGE(t + 2, (t + 2) & 3);
      asm volatile("s_waitcnt vmcnt(8)" ::: "memory");
    } else if (t == 30) {
      asm volatile("s_waitcnt vmcnt(4)" ::: "memory");
    } else {
      asm volatile("s_waitcnt vmcnt(0)" ::: "memory");
    }
    __builtin_amdgcn_s_barrier();
    asm volatile("" ::: "memory");
    const char* kb_ = (const char*)&Ks[rd][0];
    const char* vb_ = (const char*)&Vs[rd][0];
#pragma unroll
    for (int ph = 0; ph < 2; ++ph) {
      // ---- QK^T: 32 k-rows x 64 q (each a-read feeds both q-frags) ----
      f32x16 sA = (f32x16)0.0f, sB = (f32x16)0.0f;
      __builtin_amdgcn_s_setprio(1);
#pragma unroll
      for (int j = 0; j < 4; ++j) {
        int cb = j * 32 + hi * 16;
        bf16x8 a = *(const bf16x8*)(kb_ + (ph * 32 + lq) * 128 + (cb ^ swz));
        sA = __builtin_amdgcn_mfma_f32_32x32x16_bf16(a, qfA[j], sA, 0, 0, 0);
        sB = __builtin_amdgcn_mfma_f32_32x32x16_bf16(a, qfB[j], sB, 0, 0, 0);
      }
      __builtin_amdgcn_s_setprio(0);
      // ---- exp2 (raw) + packed sums ----
#pragma unroll
      for (int r = 0; r < 16; ++r) sA[r] = __builtin_amdgcn_exp2f(sA[r]);
#pragma unroll
      for (int r = 0; r < 16; ++r) sB[r] = __builtin_amdgcn_exp2f(sB[r]);
      {
        union { f32x16 v; f32x2 p[8]; } ua, ub; ua.v = sA; ub.v = sB;
        f32x2 a01 = ua.p[0] + ua.p[1], a23 = ua.p[2] + ua.p[3];
        f32x2 a45 = ua.p[4] + ua.p[5], a67 = ua.p[6] + ua.p[7];
        f32x2 ta = (a01 + a23) + (a45 + a67);
        lA += ta.x + ta.y;
        f32x2 b01 = ub.p[0] + ub.p[1], b23 = ub.p[2] + ub.p[3];
        f32x2 b45 = ub.p[4] + ub.p[5], b67 = ub.p[6] + ub.p[7];
        f32x2 tb = (b01 + b23) + (b45 + b67);
        lB += tb.x + tb.y;
      }
      // ---- pack P -> bf16 ----
      unsigned int dwA[8], dwB[8];
#pragma unroll
      for (int m = 0; m < 8; ++m) {
        asm("v_cvt_pk_bf16_f32 %0, %1, %2" : "=v"(dwA[m]) : "v"(sA[2 * m]), "v"(sA[2 * m + 1]));
        asm("v_cvt_pk_bf16_f32 %0, %1, %2" : "=v"(dwB[m]) : "v"(sB[2 * m]), "v"(sB[2 * m + 1]));
      }
      // ---- PV: each v-read feeds both q-frags; exchange via shfl_xor (proven) ----
      __builtin_amdgcn_s_setprio(1);
#pragma unroll
      for (int kk = 0; kk < 2; ++kk) {
        const int B = 4 * kk;
        unsigned int svA0 = hi ? dwA[B + 0] : dwA[B + 2];
        unsigned int svA1 = hi ? dwA[B + 1] : dwA[B + 3];
        unsigned int svB0 = hi ? dwB[B + 0] : dwB[B + 2];
        unsigned int svB1 = hi ? dwB[B + 1] : dwB[B + 3];
        unsigned int rvA0 = (unsigned int)__shfl_xor((int)svA0, 32);
        unsigned int rvA1 = (unsigned int)__shfl_xor((int)svA1, 32);
        unsigned int rvB0 = (unsigned int)__shfl_xor((int)svB0, 32);
        unsigned int rvB1 = (unsigned int)__shfl_xor((int)svB1, 32);
        union { unsigned int d[4]; bf16x8 v; } puA, puB;
        puA.d[0] = hi ? rvA0 : dwA[B + 0];
        puA.d[1] = hi ? rvA1 : dwA[B + 1];
        puA.d[2] = hi ? dwA[B + 2] : rvA0;
        puA.d[3] = hi ? dwA[B + 3] : rvA1;
        puB.d[0] = hi ? rvB0 : dwB[B + 0];
        puB.d[1] = hi ? rvB1 : dwB[B + 1];
        puB.d[2] = hi ? dwB[B + 2] : rvB0;
        puB.d[3] = hi ? dwB[B + 3] : rvB1;
        int cb = (ph * 2 + kk) * 32 + hi * 16;
        bf16x8 v0 = *(const bf16x8*)(vb_ + lq * 128 + (cb ^ swz));
        bf16x8 v1 = *(const bf16x8*)(vb_ + (32 + lq) * 128 + (cb ^ swz));
        accA0 = __builtin_amdgcn_mfma_f32_32x32x16_bf16(v0, puA.v, accA0, 0, 0, 0);
        accA1 = __builtin_amdgcn_mfma_f32_32x32x16_bf16(v1, puA.v, accA1, 0, 0, 0);
        accB0 = __builtin_amdgcn_mfma_f32_32x32x16_bf16(v0, puB.v, accB0, 0, 0, 0);
        accB1 = __builtin_amdgcn_mfma_f32_32x32x16_bf16(v1, puB.v, accB1, 0, 0, 0);
      }
      __builtin_amdgcn_s_setprio(0);
    }
  }
#undef STAGE

  // ---- epilogue: write bf16 partials for both q-frags ----
  float lsumA = lA + __shfl_xor(lA, 32);
  float lsumB = lB + __shfl_xor(lB, 32);
  size_t qrowA = (size_t)(half * 16 + bh) * NSEQ + q0 + lq;
  size_t qrowB = qrowA + 32;
  if (hi == 0) {
    lpart[qrowA] = lsumA;
    lpart[qrowB] = lsumB;
  }
  unsigned short* obA = opart + qrowA * 64;
  unsigned short* obB = opart + qrowB * 64;
#pragma unroll
  for (int rg = 0; rg < 4; ++rg) {
    unsigned int pa0[2], pa1[2], pb0[2], pb1[2];
    asm("v_cvt_pk_bf16_f32 %0, %1, %2" : "=v"(pa0[0]) : "v"(accA0[4 * rg + 0]), "v"(accA0[4 * rg + 1]));
    asm("v_cvt_pk_bf16_f32 %0, %1, %2" : "=v"(pa0[1]) : "v"(accA0[4 * rg + 2]), "v"(accA0[4 * rg + 3]));
    asm("v_cvt_pk_bf16_f32 %0, %1, %2" : "=v"(pa1[0]) : "v"(accA1[4 * rg + 0]), "v"(accA1[4 * rg + 1]));
    asm("v_cvt_pk_bf16_f32 %0, %1, %2" : "=v"(pa1[1]) : "v"(accA1[4 * rg + 2]), "v"(accA1[4 * rg + 3]));
    asm("v_cvt_pk_bf16_f32 %0, %1, %2" : "=v"(pb0[0]) : "v"(accB0[4 * rg + 0]), "v"(accB0[4 * rg + 1]));
    asm("v_cvt_pk_bf16_f32 %0, %1, %2" : "=v"(pb0[1]) : "v"(accB0[4 * rg + 2]), "v"(accB0[4 * rg + 3]));
    asm("v_cvt_pk_bf16_f32 %0, %1, %2" : "=v"(pb1[0]) : "v"(accB1[4 * rg + 0]), "v"(accB1[4 * rg + 1]));
    asm("v_cvt_pk_bf16_f32 %0, %1, %2" : "=v"(pb1[1]) : "v"(accB1[4 * rg + 2]), "v"(accB1[4 * rg + 3]));
    *(uint2*)(obA + 8 * rg + 4 * hi) = *(uint2*)pa0;
    *(uint2*)(obA + 32 + 8 * rg + 4 * hi) = *(uint2*)pa1;
    *(uint2*)(obB + 8 * rg + 4 * hi) = *(uint2*)pb0;
    *(uint2*)(obB + 32 + 8 * rg + 4 * hi) = *(uint2*)pb1;
  }
}

extern "C" void kernel_launch(void* const* d_in, const int* in_sizes, int n_in,
                              void* d_out, int out_size, void* d_ws, size_t ws_size,
                              hipStream_t stream) {
  const float* x    = (const float*)d_in[0];
  const float* rot  = (const float*)d_in[1];
  const float* lnw  = (const float*)d_in[2];
  const float* lnb  = (const float*)d_in[3];
  const float* wqkv = (const float*)d_in[4];
  const float* wout = (const float*)d_in[5];
  const float* bout = (const float*)d_in[6];
  float* out = (float*)d_out;

  char* ws = (char*)d_ws;
  const size_t MB = (size_t)1 << 20;
  float* cosT          = (float*)(ws + 0 * MB);        // 2 MB
  float* sinT          = (float*)(ws + 2 * MB);        // 2 MB
  unsigned short* wqkb = (unsigned short*)(ws + 4 * MB);   // 1.5 MB (dead after gemm0)
  float* lpart         = (float*)(ws + 5 * MB + 512 * 1024); // 512 KB
  unsigned short* wob  = (unsigned short*)(ws + 6 * MB);   // 0.5 MB
  unsigned short* xn   = (unsigned short*)(ws + 8 * MB);   // 8 MB (dead after gemm0)
  unsigned short* opart = (unsigned short*)(ws + 8 * MB);  // 16 MB bf16 (8-24, attn -> gemm_out)
  unsigned short* qkv  = (unsigned short*)(ws + 16 * MB);  // 24 MB (dead after rope_split)
  unsigned short* qh   = (unsigned short*)(ws + 40 * MB);  // 8 MB (dead after attn)
  unsigned short* kh   = (unsigned short*)(ws + 48 * MB);  // 8 MB
  unsigned short* vt   = (unsigned short*)(ws + 56 * MB);  // 8 MB

  k_prep<<<8192, 256, 0, stream>>>(rot, cosT, sinT, wqkv, wqkb, wout, wob,
                                   x, lnw, lnb, xn);
  k_gemm<<<dim3(NROWS / 128, QKVN / 128), 256, 0, stream>>>(xn, wqkb, qkv,
                                                            NROWS, QKVN, DIM);
  k_rope_split<<<dim3(NSEQ / 128, 16), 256, 0, stream>>>(qkv, cosT, sinT, qh, kh, vt);
  k_attn<<<512, 256, 0, stream>>>(qh, kh, vt, opart, lpart);
  k_gemm_out<<<dim3(NROWS / 64, DIM / 128), 256, 0, stream>>>(opart, lpart, cosT, sinT,
                                                              wob, out, bout);
}

// Round 17
// 134.342 us; speedup vs baseline: 1.0311x; 1.0311x over previous
//
#include <hip/hip_runtime.h>
#include <cmath>

typedef short bf16x8 __attribute__((ext_vector_type(8)));
typedef float f32x2 __attribute__((ext_vector_type(2)));
typedef float f32x4 __attribute__((ext_vector_type(4)));
typedef float f32x16 __attribute__((ext_vector_type(16)));

#define NSEQ 4096
#define BATCH 2
#define DIM 512
#define HEADS 8
#define NROWS (BATCH * NSEQ)   // 8192
#define QKVN (3 * DIM)         // 1536

__device__ __forceinline__ unsigned short f2bf(float f) {
  unsigned int u = __float_as_uint(f);
  u += 0x7fffu + ((u >> 16) & 1u);
  return (unsigned short)(u >> 16);
}
__device__ __forceinline__ float bf2f(unsigned short h) {
  return __uint_as_float(((unsigned int)h) << 16);
}
__device__ __forceinline__ void gload16(const unsigned short* g, unsigned short* l) {
  __builtin_amdgcn_global_load_lds((const __attribute__((address_space(1))) unsigned int*)g,
                                   (__attribute__((address_space(3))) unsigned int*)l, 16, 0, 0);
}

// ---------------- fused prep: trig tables (HW sin/cos) + weight cvts + LayerNorm ----------------
// blocks [0,2048): tables; [2048,5120): wqkv cvt; [5120,6144): wout cvt; [6144,8192): LN
__global__ __launch_bounds__(256) void k_prep(const float* __restrict__ rot,
                                              float* __restrict__ cosT,
                                              float* __restrict__ sinT,
                                              const float* __restrict__ wqkv,
                                              unsigned short* __restrict__ wqkb,
                                              const float* __restrict__ wout,
                                              unsigned short* __restrict__ wob,
                                              const float* __restrict__ x,
                                              const float* __restrict__ lnw,
                                              const float* __restrict__ lnb,
                                              unsigned short* __restrict__ xn) {
  const float INV2PI = 0.15915494309f;
  int bid = blockIdx.x;
  int t = threadIdx.x;
  if (bid < 2048) {
    int i = bid * 256 + t;
    float rv = rot[i] * INV2PI;           // v_sin/v_cos take revolutions
    cosT[i] = __builtin_amdgcn_cosf(rv);
    sinT[i] = __builtin_amdgcn_sinf(rv);
  } else if (bid < 5120) {
    int i = (bid - 2048) * 256 + t;
    wqkb[i] = f2bf(wqkv[i]);
  } else if (bid < 6144) {
    int i = (bid - 5120) * 256 + t;
    wob[i] = f2bf(wout[i]);
  } else {
    int row = (bid - 6144) * 4 + (t >> 6);
    int lane = t & 63;
    const float* xr = x + (size_t)row * DIM;
    float v[8];
    float s = 0.f;
#pragma unroll
    for (int j = 0; j < 8; ++j) { v[j] = xr[lane + j * 64]; s += v[j]; }
#pragma unroll
    for (int m = 1; m < 64; m <<= 1) s += __shfl_xor(s, m);
    float mu = s * (1.0f / DIM);
    float q = 0.f;
#pragma unroll
    for (int j = 0; j < 8; ++j) { float d = v[j] - mu; q += d * d; }
#pragma unroll
    for (int m = 1; m < 64; m <<= 1) q += __shfl_xor(q, m);
    float rs = rsqrtf(q * (1.0f / DIM) + 1e-5f);
#pragma unroll
    for (int j = 0; j < 8; ++j) {
      int col = lane + j * 64;
      xn[(size_t)row * DIM + col] = f2bf((v[j] - mu) * rs * lnw[col] + lnb[col]);
    }
  }
}

// ---------------- GEMM: C = A[M][K] * B[N][K]^T — 3-buffer ring, counted vmcnt ----
// TM = block M-tile (128 or 64); N-tile fixed 128. 4 waves: wave tile (TM/2) x 64.
template <int EPI, int TM>
__global__ __launch_bounds__(256) void k_gemm(const unsigned short* __restrict__ A,
                                              const unsigned short* __restrict__ B,
                                              void* __restrict__ C,
                                              const float* __restrict__ bias,
                                              int M, int N, int K) {
  constexpr int MI = TM / 32;  // acc rows per wave (4 or 2)
  __shared__ __align__(16) unsigned short As[3][TM * 32];
  __shared__ __align__(16) unsigned short Bs[3][128 * 32];
  int bm = blockIdx.x, bn = blockIdx.y;
  int tid = threadIdx.x;
  int lane = tid & 63, w = tid >> 6;
  int wm = (w >> 1) * (TM / 2), wn = (w & 1) << 6;
  f32x4 acc[MI][4] = {};

#define GSTAGE(KT, BUF) do { \
  if constexpr (TM == 128) { \
    _Pragma("unroll") \
    for (int i = 0; i < 2; ++i) { \
      int c = tid + (i << 8); \
      int row = c >> 2, kc = (c & 3) << 3; \
      gload16(A + (size_t)(bm * 128 + row) * K + (KT) + kc, &As[BUF][(w * 64 + i * 256) * 8]); \
    } \
  } else { \
    int row = tid >> 2, kc = (tid & 3) << 3; \
    gload16(A + (size_t)(bm * 64 + row) * K + (KT) + kc, &As[BUF][(w * 64) * 8]); \
  } \
  _Pragma("unroll") \
  for (int i = 0; i < 2; ++i) { \
    int c = tid + (i << 8); \
    int row = c >> 2, kc = (c & 3) << 3; \
    gload16(B + (size_t)(bn * 128 + row) * K + (KT) + kc, &Bs[BUF][(w * 64 + i * 256) * 8]); \
  } } while (0)

  GSTAGE(0, 0);
  int nk = K >> 5;
  int rbuf = 0, wbuf = 1;
  for (int t = 0; t < nk; ++t) {
    if (t + 1 < nk) {
      GSTAGE((t + 1) << 5, wbuf);
      if constexpr (TM == 128) {
        asm volatile("s_waitcnt vmcnt(4)" ::: "memory");
      } else {
        asm volatile("s_waitcnt vmcnt(3)" ::: "memory");
      }
    } else {
      asm volatile("s_waitcnt vmcnt(0)" ::: "memory");
    }
    __builtin_amdgcn_s_barrier();
    asm volatile("" ::: "memory");
    bf16x8 af[MI], bfr[4];
#pragma unroll
    for (int mi = 0; mi < MI; ++mi)
      af[mi] = *(const bf16x8*)&As[rbuf][(wm + mi * 16 + (lane & 15)) * 32 + ((lane >> 4) << 3)];
#pragma unroll
    for (int ni = 0; ni < 4; ++ni)
      bfr[ni] = *(const bf16x8*)&Bs[rbuf][(wn + ni * 16 + (lane & 15)) * 32 + ((lane >> 4) << 3)];
#pragma unroll
    for (int mi = 0; mi < MI; ++mi)
#pragma unroll
      for (int ni = 0; ni < 4; ++ni)
        acc[mi][ni] = __builtin_amdgcn_mfma_f32_16x16x32_bf16(af[mi], bfr[ni], acc[mi][ni], 0, 0, 0);
    rbuf = (rbuf == 2) ? 0 : rbuf + 1;
    wbuf = (wbuf == 2) ? 0 : wbuf + 1;
  }
#undef GSTAGE
#pragma unroll
  for (int mi = 0; mi < MI; ++mi) {
#pragma unroll
    for (int ni = 0; ni < 4; ++ni) {
#pragma unroll
      for (int r = 0; r < 4; ++r) {
        int gm = bm * TM + wm + mi * 16 + ((lane >> 4) << 2) + r;
        int gn = bn * 128 + wn + ni * 16 + (lane & 15);
        if (EPI == 0) {
          ((unsigned short*)C)[(size_t)gm * N + gn] = f2bf(acc[mi][ni][r]);
        } else {
          ((float*)C)[(size_t)gm * N + gn] = acc[mi][ni][r] + bias[gn];
        }
      }
    }
  }
}

// ------ RoPE + head split (+ V transpose); Q pre-scaled by 0.125*log2(e) (exp2-domain) ------
__global__ __launch_bounds__(256) void k_rope_split(const unsigned short* __restrict__ qkv,
                                                    const float* __restrict__ cosT,
                                                    const float* __restrict__ sinT,
                                                    unsigned short* __restrict__ qh,
                                                    unsigned short* __restrict__ kh,
                                                    unsigned short* __restrict__ vt) {
  __shared__ unsigned short vs[128][65];
  const float QSC = 0.125f * 1.44269504f;
  int nt = blockIdx.x, bh = blockIdx.y;
  int b = bh >> 3, h = bh & 7;
  int n0 = nt * 128;
  int t = threadIdx.x;
  int sub = t >> 3, cc = t & 7;
#pragma unroll
  for (int rr = 0; rr < 4; ++rr) {
    int row = rr * 32 + sub;
    int n = n0 + row;
    size_t base = ((size_t)(b * NSEQ + n)) * QKVN + h * 64 + cc * 8;
    const float* cb = cosT + ((size_t)(b * NSEQ + n)) * 64 + cc * 8;
    const float* sb = sinT + ((size_t)(b * NSEQ + n)) * 64 + cc * 8;
    float c[8], sn[8];
#pragma unroll
    for (int j = 0; j < 8; ++j) { c[j] = cb[j]; sn[j] = sb[j]; }
    bf16x8 qv = *(const bf16x8*)(qkv + base);
    bf16x8 kv = *(const bf16x8*)(qkv + base + 512);
    bf16x8 vv = *(const bf16x8*)(qkv + base + 1024);
    union { bf16x8 v; unsigned short u[8]; } yq, yk;
#pragma unroll
    for (int j = 0; j < 8; j += 2) {
      {
        float e = bf2f((unsigned short)qv[j]), o = bf2f((unsigned short)qv[j + 1]);
        yq.u[j]     = f2bf((e * c[j] - o * sn[j]) * QSC);
        yq.u[j + 1] = f2bf((o * c[j + 1] + e * sn[j + 1]) * QSC);
      }
      {
        float e = bf2f((unsigned short)kv[j]), o = bf2f((unsigned short)kv[j + 1]);
        yk.u[j]     = f2bf(e * c[j] - o * sn[j]);
        yk.u[j + 1] = f2bf(o * c[j + 1] + e * sn[j + 1]);
      }
      {
        float e = bf2f((unsigned short)vv[j]), o = bf2f((unsigned short)vv[j + 1]);
        vs[row][cc * 8 + j]     = f2bf(e * c[j] - o * sn[j]);
        vs[row][cc * 8 + j + 1] = f2bf(o * c[j + 1] + e * sn[j + 1]);
      }
    }
    *(bf16x8*)(qh + ((size_t)bh * NSEQ + n) * 64 + cc * 8) = yq.v;
    *(bf16x8*)(kh + ((size_t)bh * NSEQ + n) * 64 + cc * 8) = yk.v;
  }
  __syncthreads();
  int d = t >> 2, c4 = t & 3;
#pragma unroll
  for (int g = 0; g < 4; ++g) {
    union { bf16x8 v; unsigned short u[8]; } tv;
#pragma unroll
    for (int j = 0; j < 8; ++j) tv.u[j] = vs[c4 * 32 + g * 8 + j][d];
    *(bf16x8*)(vt + ((size_t)bh * 64 + d) * NSEQ + n0 + c4 * 32 + g * 8) = tv.v;
  }
}

// ---------------- Flash attention: KV-split-2, 64q/wave, counted-vmcnt pipeline ----
// 512 blocks x 4 waves; 4-buffer LDS ring, depth-2 prefetch, counted vmcnt(8) + raw
// s_barrier per tile (never drain in steady state). shfl_xor exchange (proven).
__global__ __launch_bounds__(256, 2) void k_attn(const unsigned short* __restrict__ Qh,
                                                 const unsigned short* __restrict__ Kh,
                                                 const unsigned short* __restrict__ VT,
                                                 unsigned short* __restrict__ opart,
                                                 float* __restrict__ lpart) {
  __shared__ __align__(16) unsigned short Ks[4][64 * 64];
  __shared__ __align__(16) unsigned short Vs[4][64 * 64];
  int bid = blockIdx.x;
  int bh   = (bid & 7) + 8 * ((bid >> 7) & 1);  // XCD-pinned: bh%8 == bid%8
  int qt   = (bid >> 3) & 15;
  int half = (bid >> 8) & 1;
  int tid = threadIdx.x;
  int w = tid >> 6, lane = tid & 63;
  int lq = lane & 31, hi = lane >> 5;
  int q0 = qt * 256 + w * 64;
  int kv0 = half * 2048;

  const unsigned short* Kbh = Kh + (size_t)bh * NSEQ * 64;
  const unsigned short* Vbh = VT + (size_t)bh * 64 * NSEQ;

  const unsigned short* QbA = Qh + ((size_t)bh * NSEQ + q0 + lq) * 64 + hi * 8;
  const unsigned short* QbB = QbA + 32 * 64;
  bf16x8 qfA[4], qfB[4];
#pragma unroll
  for (int j = 0; j < 4; ++j) {
    qfA[j] = *(const bf16x8*)(QbA + j * 16);
    qfB[j] = *(const bf16x8*)(QbB + j * 16);
  }

  // staging chunk geometry: chunk c -> row r=c>>3, source 16B slot (c&7)^(r&7)
  int c0 = w * 64 + lane;
  int r0 = c0 >> 3, sw0 = ((c0 & 7) ^ (r0 & 7)) << 3;
  int c1 = c0 + 256;
  int r1 = c1 >> 3, sw1 = ((c1 & 7) ^ (r1 & 7)) << 3;
  int ld0 = (w * 64) * 8, ld1 = (256 + w * 64) * 8;

  f32x16 accA0 = (f32x16)0.0f, accA1 = (f32x16)0.0f;
  f32x16 accB0 = (f32x16)0.0f, accB1 = (f32x16)0.0f;
  float lA = 0.f, lB = 0.f;
  int swz = (lq & 7) << 4;

#define STAGE(T, BUF) do { \
  int tg_ = kv0 + (T) * 64; \
  gload16(Kbh + ((size_t)tg_ + r0) * 64 + sw0, &Ks[BUF][ld0]); \
  gload16(Kbh + ((size_t)tg_ + r1) * 64 + sw1, &Ks[BUF][ld1]); \
  gload16(Vbh + (size_t)r0 * NSEQ + tg_ + sw0, &Vs[BUF][ld0]); \
  gload16(Vbh + (size_t)r1 * NSEQ + tg_ + sw1, &Vs[BUF][ld1]); \
} while (0)

  // prologue: prefetch tiles 0 and 1 (8 loads in flight)
  STAGE(0, 0);
  STAGE(1, 1);

  for (int t = 0; t < 32; ++t) {
    int rd = t & 3;
    if (t < 30) {
      STAGE(t + 2, (t + 2) & 3);
      asm volatile("s_waitcnt vmcnt(8)" ::: "memory");
    } else if (t == 30) {
      asm volatile("s_waitcnt vmcnt(4)" ::: "memory");
    } else {
      asm volatile("s_waitcnt vmcnt(0)" ::: "memory");
    }
    __builtin_amdgcn_s_barrier();
    asm volatile("" ::: "memory");
    const char* kb_ = (const char*)&Ks[rd][0];
    const char* vb_ = (const char*)&Vs[rd][0];
#pragma unroll
    for (int ph = 0; ph < 2; ++ph) {
      // ---- QK^T: 32 k-rows x 64 q (each a-read feeds both q-frags) ----
      f32x16 sA = (f32x16)0.0f, sB = (f32x16)0.0f;
      __builtin_amdgcn_s_setprio(1);
#pragma unroll
      for (int j = 0; j < 4; ++j) {
        int cb = j * 32 + hi * 16;
        bf16x8 a = *(const bf16x8*)(kb_ + (ph * 32 + lq) * 128 + (cb ^ swz));
        sA = __builtin_amdgcn_mfma_f32_32x32x16_bf16(a, qfA[j], sA, 0, 0, 0);
        sB = __builtin_amdgcn_mfma_f32_32x32x16_bf16(a, qfB[j], sB, 0, 0, 0);
      }
      __builtin_amdgcn_s_setprio(0);
      // ---- exp2 (raw) + packed sums ----
#pragma unroll
      for (int r = 0; r < 16; ++r) sA[r] = __builtin_amdgcn_exp2f(sA[r]);
#pragma unroll
      for (int r = 0; r < 16; ++r) sB[r] = __builtin_amdgcn_exp2f(sB[r]);
      {
        union { f32x16 v; f32x2 p[8]; } ua, ub; ua.v = sA; ub.v = sB;
        f32x2 a01 = ua.p[0] + ua.p[1], a23 = ua.p[2] + ua.p[3];
        f32x2 a45 = ua.p[4] + ua.p[5], a67 = ua.p[6] + ua.p[7];
        f32x2 ta = (a01 + a23) + (a45 + a67);
        lA += ta.x + ta.y;
        f32x2 b01 = ub.p[0] + ub.p[1], b23 = ub.p[2] + ub.p[3];
        f32x2 b45 = ub.p[4] + ub.p[5], b67 = ub.p[6] + ub.p[7];
        f32x2 tb = (b01 + b23) + (b45 + b67);
        lB += tb.x + tb.y;
      }
      // ---- pack P -> bf16 ----
      unsigned int dwA[8], dwB[8];
#pragma unroll
      for (int m = 0; m < 8; ++m) {
        asm("v_cvt_pk_bf16_f32 %0, %1, %2" : "=v"(dwA[m]) : "v"(sA[2 * m]), "v"(sA[2 * m + 1]));
        asm("v_cvt_pk_bf16_f32 %0, %1, %2" : "=v"(dwB[m]) : "v"(sB[2 * m]), "v"(sB[2 * m + 1]));
      }
      // ---- PV: each v-read feeds both q-frags; exchange via shfl_xor (proven) ----
      __builtin_amdgcn_s_setprio(1);
#pragma unroll
      for (int kk = 0; kk < 2; ++kk) {
        const int B = 4 * kk;
        unsigned int svA0 = hi ? dwA[B + 0] : dwA[B + 2];
        unsigned int svA1 = hi ? dwA[B + 1] : dwA[B + 3];
        unsigned int svB0 = hi ? dwB[B + 0] : dwB[B + 2];
        unsigned int svB1 = hi ? dwB[B + 1] : dwB[B + 3];
        unsigned int rvA0 = (unsigned int)__shfl_xor((int)svA0, 32);
        unsigned int rvA1 = (unsigned int)__shfl_xor((int)svA1, 32);
        unsigned int rvB0 = (unsigned int)__shfl_xor((int)svB0, 32);
        unsigned int rvB1 = (unsigned int)__shfl_xor((int)svB1, 32);
        union { unsigned int d[4]; bf16x8 v; } puA, puB;
        puA.d[0] = hi ? rvA0 : dwA[B + 0];
        puA.d[1] = hi ? rvA1 : dwA[B + 1];
        puA.d[2] = hi ? dwA[B + 2] : rvA0;
        puA.d[3] = hi ? dwA[B + 3] : rvA1;
        puB.d[0] = hi ? rvB0 : dwB[B + 0];
        puB.d[1] = hi ? rvB1 : dwB[B + 1];
        puB.d[2] = hi ? dwB[B + 2] : rvB0;
        puB.d[3] = hi ? dwB[B + 3] : rvB1;
        int cb = (ph * 2 + kk) * 32 + hi * 16;
        bf16x8 v0 = *(const bf16x8*)(vb_ + lq * 128 + (cb ^ swz));
        bf16x8 v1 = *(const bf16x8*)(vb_ + (32 + lq) * 128 + (cb ^ swz));
        accA0 = __builtin_amdgcn_mfma_f32_32x32x16_bf16(v0, puA.v, accA0, 0, 0, 0);
        accA1 = __builtin_amdgcn_mfma_f32_32x32x16_bf16(v1, puA.v, accA1, 0, 0, 0);
        accB0 = __builtin_amdgcn_mfma_f32_32x32x16_bf16(v0, puB.v, accB0, 0, 0, 0);
        accB1 = __builtin_amdgcn_mfma_f32_32x32x16_bf16(v1, puB.v, accB1, 0, 0, 0);
      }
      __builtin_amdgcn_s_setprio(0);
    }
  }
#undef STAGE

  // ---- epilogue: write bf16 partials for both q-frags ----
  float lsumA = lA + __shfl_xor(lA, 32);
  float lsumB = lB + __shfl_xor(lB, 32);
  size_t qrowA = (size_t)(half * 16 + bh) * NSEQ + q0 + lq;
  size_t qrowB = qrowA + 32;
  if (hi == 0) {
    lpart[qrowA] = lsumA;
    lpart[qrowB] = lsumB;
  }
  unsigned short* obA = opart + qrowA * 64;
  unsigned short* obB = opart + qrowB * 64;
#pragma unroll
  for (int rg = 0; rg < 4; ++rg) {
    unsigned int pa0[2], pa1[2], pb0[2], pb1[2];
    asm("v_cvt_pk_bf16_f32 %0, %1, %2" : "=v"(pa0[0]) : "v"(accA0[4 * rg + 0]), "v"(accA0[4 * rg + 1]));
    asm("v_cvt_pk_bf16_f32 %0, %1, %2" : "=v"(pa0[1]) : "v"(accA0[4 * rg + 2]), "v"(accA0[4 * rg + 3]));
    asm("v_cvt_pk_bf16_f32 %0, %1, %2" : "=v"(pa1[0]) : "v"(accA1[4 * rg + 0]), "v"(accA1[4 * rg + 1]));
    asm("v_cvt_pk_bf16_f32 %0, %1, %2" : "=v"(pa1[1]) : "v"(accA1[4 * rg + 2]), "v"(accA1[4 * rg + 3]));
    asm("v_cvt_pk_bf16_f32 %0, %1, %2" : "=v"(pb0[0]) : "v"(accB0[4 * rg + 0]), "v"(accB0[4 * rg + 1]));
    asm("v_cvt_pk_bf16_f32 %0, %1, %2" : "=v"(pb0[1]) : "v"(accB0[4 * rg + 2]), "v"(accB0[4 * rg + 3]));
    asm("v_cvt_pk_bf16_f32 %0, %1, %2" : "=v"(pb1[0]) : "v"(accB1[4 * rg + 0]), "v"(accB1[4 * rg + 1]));
    asm("v_cvt_pk_bf16_f32 %0, %1, %2" : "=v"(pb1[1]) : "v"(accB1[4 * rg + 2]), "v"(accB1[4 * rg + 3]));
    *(uint2*)(obA + 8 * rg + 4 * hi) = *(uint2*)pa0;
    *(uint2*)(obA + 32 + 8 * rg + 4 * hi) = *(uint2*)pa1;
    *(uint2*)(obB + 8 * rg + 4 * hi) = *(uint2*)pb0;
    *(uint2*)(obB + 32 + 8 * rg + 4 * hi) = *(uint2*)pb1;
  }
}

// ---------------- combine 2 halves (bf16) + normalize + inverse RoPE -> ao ----------------
__global__ __launch_bounds__(256) void k_combine(const unsigned short* __restrict__ opart,
                                                 const float* __restrict__ lpart,
                                                 const float* __restrict__ cosT,
                                                 const float* __restrict__ sinT,
                                                 unsigned short* __restrict__ ao) {
  int bh = blockIdx.y;
  int b = bh >> 3, h = bh & 7;
  int t = threadIdx.x;
  int q = blockIdx.x * 16 + (t >> 4);
  int d = (t & 15) * 4;
  size_t i0 = (size_t)bh * NSEQ + q;
  const size_t HOFF = (size_t)16 * NSEQ;
  float l = lpart[i0] + lpart[i0 + HOFF];
  float o[4] = {0.f, 0.f, 0.f, 0.f};
#pragma unroll
  for (int p = 0; p < 2; ++p) {
    uint2 u = *(const uint2*)(opart + (i0 + p * HOFF) * 64 + d);
    o[0] += bf2f((unsigned short)(u.x & 0xffff));
    o[1] += bf2f((unsigned short)(u.x >> 16));
    o[2] += bf2f((unsigned short)(u.y & 0xffff));
    o[3] += bf2f((unsigned short)(u.y >> 16));
  }
  float inv = 1.0f / l;
  float4 c4 = *(const float4*)(cosT + ((size_t)b * NSEQ + q) * 64 + d);
  float4 s4 = *(const float4*)(sinT + ((size_t)b * NSEQ + q) * 64 + d);
  float yx = o[0] * inv;
  float yy = o[1] * inv;
  float yz = o[2] * inv;
  float yw = o[3] * inv;
  float r0 = yx * c4.x + yy * s4.x;
  float r1 = yy * c4.y - yx * s4.y;
  float r2 = yz * c4.z + yw * s4.z;
  float r3 = yw * c4.w - yz * s4.w;
  unsigned int w0, w1;
  asm("v_cvt_pk_bf16_f32 %0, %1, %2" : "=v"(w0) : "v"(r0), "v"(r1));
  asm("v_cvt_pk_bf16_f32 %0, %1, %2" : "=v"(w1) : "v"(r2), "v"(r3));
  unsigned int uu[2] = {w0, w1};
  *(uint2*)(ao + ((size_t)b * NSEQ + q) * DIM + h * 64 + d) = *(uint2*)uu;
}

extern "C" void kernel_launch(void* const* d_in, const int* in_sizes, int n_in,
                              void* d_out, int out_size, void* d_ws, size_t ws_size,
                              hipStream_t stream) {
  const float* x    = (const float*)d_in[0];
  const float* rot  = (const float*)d_in[1];
  const float* lnw  = (const float*)d_in[2];
  const float* lnb  = (const float*)d_in[3];
  const float* wqkv = (const float*)d_in[4];
  const float* wout = (const float*)d_in[5];
  const float* bout = (const float*)d_in[6];
  float* out = (float*)d_out;

  char* ws = (char*)d_ws;
  const size_t MB = (size_t)1 << 20;
  float* cosT          = (float*)(ws + 0 * MB);        // 2 MB
  float* sinT          = (float*)(ws + 2 * MB);        // 2 MB
  unsigned short* wqkb = (unsigned short*)(ws + 4 * MB);   // 1.5 MB (dead after gemm0)
  float* lpart         = (float*)(ws + 5 * MB + 512 * 1024); // 512 KB
  unsigned short* wob  = (unsigned short*)(ws + 6 * MB);   // 0.5 MB
  unsigned short* xn   = (unsigned short*)(ws + 8 * MB);   // 8 MB (dead after gemm0)
  unsigned short* opart = (unsigned short*)(ws + 8 * MB);  // 16 MB bf16 (8-24, attn -> combine)
  unsigned short* qkv  = (unsigned short*)(ws + 16 * MB);  // 24 MB (dead after rope_split)
  unsigned short* qh   = (unsigned short*)(ws + 40 * MB);  // 8 MB (dead after attn)
  unsigned short* ao   = (unsigned short*)(ws + 40 * MB);  // 8 MB (combine -> gemm1)
  unsigned short* kh   = (unsigned short*)(ws + 48 * MB);  // 8 MB
  unsigned short* vt   = (unsigned short*)(ws + 56 * MB);  // 8 MB

  k_prep<<<8192, 256, 0, stream>>>(rot, cosT, sinT, wqkv, wqkb, wout, wob,
                                   x, lnw, lnb, xn);
  k_gemm<0, 128><<<dim3(NROWS / 128, QKVN / 128), 256, 0, stream>>>(xn, wqkb, qkv, nullptr,
                                                                    NROWS, QKVN, DIM);
  k_rope_split<<<dim3(NSEQ / 128, 16), 256, 0, stream>>>(qkv, cosT, sinT, qh, kh, vt);
  k_attn<<<512, 256, 0, stream>>>(qh, kh, vt, opart, lpart);
  k_combine<<<dim3(NSEQ / 16, 16), 256, 0, stream>>>(opart, lpart, cosT, sinT, ao);
  k_gemm<1, 64><<<dim3(NROWS / 64, DIM / 128), 256, 0, stream>>>(ao, wob, out, bout,
                                                                 NROWS, DIM, DIM);
}